// Round 6
// baseline (551.361 us; speedup 1.0000x reference)
//
#include <hip/hip_runtime.h>
#include <hip/hip_bf16.h>

// R6 = MEASUREMENT ROUND. Identical kernels to R4 (best: 140.1 us), but the
// dominant fused kernel is launched 5x (idempotent, deterministic) so its
// per-invocation cost can be recovered as F = (dur_R6 - dur_R4) / 4.

#define QUERY_DIM 128
#define HIDDEN 128

typedef float f32x4 __attribute__((ext_vector_type(4)));

__device__ __forceinline__ float dot4(f32x4 a, f32x4 b) {
    return a.x * b.x + a.y * b.y + a.z * b.z + a.w * b.w;
}

// ---------------------------------------------------------------------------
// Kernel 1 (combo): blocks 0..63  -> W[e][d] = sum_h WQ[h][e]*WK[h][d]
//                   blocks 64..   -> segment starts via binary search
// ---------------------------------------------------------------------------
__global__ __launch_bounds__(256) void combo_kernel(const float* __restrict__ WQ,
                                                    const float* __restrict__ WK,
                                                    float* __restrict__ W,
                                                    const int* __restrict__ idx,
                                                    int* __restrict__ start,
                                                    int nmols, int total) {
    int b = blockIdx.x;
    int t = threadIdx.x;
    if (b < 64) {
        int e = b * 2 + (t >> 7);   // 0..127
        int d = t & 127;
        float acc = 0.f;
#pragma unroll 8
        for (int h = 0; h < HIDDEN; ++h) {
            acc += WQ[h * QUERY_DIM + e] * WK[h * 128 + d];
        }
        W[e * 128 + d] = acc;
    } else {
        int m = (b - 64) * 256 + t;
        if (m > nmols) return;
        if (m == nmols) { start[m] = total; return; }
        int lo = 0, hi = total;
        while (lo < hi) {
            int mid = (lo + hi) >> 1;
            if (idx[mid] < m) lo = mid + 1; else hi = mid;
        }
        start[m] = lo;
    }
}

// ---------------------------------------------------------------------------
// Kernel 2: R = query @ W    [nmols,128]. 16 rows/block, 256 threads.
// ---------------------------------------------------------------------------
__global__ __launch_bounds__(256) void qproj_kernel(const float* __restrict__ Q,
                                                    const float* __restrict__ W,
                                                    float* __restrict__ R, int nmols) {
    __shared__ float wl[64 * 128];  // 32 KB (half of W)
    __shared__ float ql[16 * 128];  // 8 KB (16 query rows)
    int t = threadIdx.x;
    int c = t & 127;
    int g = t >> 7;
    long row0 = (long)blockIdx.x * 16;

    for (int i = t * 4; i < 16 * 128; i += 256 * 4) {
        *(float4*)&ql[i] = *(const float4*)&Q[row0 * QUERY_DIM + i];
    }

    float acc[8] = {0.f, 0.f, 0.f, 0.f, 0.f, 0.f, 0.f, 0.f};

    for (int half = 0; half < 2; ++half) {
        __syncthreads();
        for (int i = t * 4; i < 64 * 128; i += 256 * 4) {
            *(float4*)&wl[i] = *(const float4*)&W[half * 64 * 128 + i];
        }
        __syncthreads();
        for (int d = 0; d < 64; ++d) {
            float wv = wl[d * 128 + c];
            int dg = half * 64 + d;
#pragma unroll
            for (int r = 0; r < 8; ++r) {
                acc[r] += ql[(g * 8 + r) * 128 + dg] * wv;
            }
        }
    }
#pragma unroll
    for (int r = 0; r < 8; ++r) {
        long row = row0 + g * 8 + r;
        if (row < nmols) R[row * 128 + c] = acc[r];
    }
}

// ---------------------------------------------------------------------------
// Kernel 3 (fused, dominant — R4 version): per segment scores + softmax.
// One wave per segment; half-wave per key (contiguous 512B row per half);
// wave instruction covers 1KB contiguous (rows k, k+1).
// ---------------------------------------------------------------------------
__global__ __launch_bounds__(256) void fused_kernel(const float* __restrict__ K,
                                                    const float* __restrict__ R,
                                                    const int* __restrict__ start,
                                                    float* __restrict__ weights,
                                                    float* scores,   // no restrict: store+load alias
                                                    int nmols) {
    const int lane = threadIdx.x & 63;
    const int half = lane >> 5;      // 0/1
    const int hl = lane & 31;        // lane within half-wave
    const int wave = (blockIdx.x * 256 + threadIdx.x) >> 6;
    const int nwaves = gridDim.x * 4;
    const float sc = 0.08838834764831845f;  // 1/sqrt(128)

    for (int s = wave; s < nmols; s += nwaves) {
        int s0 = start[s], s1 = start[s + 1];
        if (s0 >= s1) continue;

        f32x4 rfrag = *((const f32x4*)(R + (long)s * 128) + hl);

        // ---- phase 1: scores + running max ----
        float mx = -__builtin_inff();
        for (int k = s0 + half; k < s1; k += 2) {
            f32x4 kv = __builtin_nontemporal_load((const f32x4*)(K + (long)k * 128) + hl);
            float v = dot4(kv, rfrag);
#pragma unroll
            for (int off = 16; off > 0; off >>= 1) v += __shfl_xor(v, off, 64);
            v *= sc;
            if (hl == 0) scores[k] = v;
            mx = fmaxf(mx, v);
        }
        mx = fmaxf(mx, __shfl_xor(mx, 32, 64));

        asm volatile("s_waitcnt vmcnt(0)" ::: "memory");

        // ---- phase 2: sum of exp ----
        float sum = 0.f;
        for (int i = s0 + lane; i < s1; i += 64) sum += __expf(scores[i] - mx);
#pragma unroll
        for (int off = 32; off > 0; off >>= 1) sum += __shfl_xor(sum, off, 64);
        float inv = 1.0f / sum;

        // ---- phase 3: weights ----
        for (int i = s0 + lane; i < s1; i += 64)
            weights[i] = __expf(scores[i] - mx) * inv;
    }
}

// ---------------------------------------------------------------------------
extern "C" void kernel_launch(void* const* d_in, const int* in_sizes, int n_in,
                              void* d_out, int out_size, void* d_ws, size_t ws_size,
                              hipStream_t stream) {
    const float* Q   = (const float*)d_in[0];
    const float* K   = (const float*)d_in[1];
    const float* WQ  = (const float*)d_in[2];
    const float* WK  = (const float*)d_in[3];
    const int*   idx = (const int*)d_in[4];

    const int nmols = in_sizes[0] / QUERY_DIM;   // 16384
    const int total = in_sizes[4];               // 1048576

    float* weights = (float*)d_out;              // output 0
    float* scores  = (float*)d_out + total;      // output 1

    char* ws = (char*)d_ws;
    float* W        = (float*)ws;                        // 64 KB
    int*   segstart = (int*)(ws + 65536);                // (nmols+1)*4
    float* R        = (float*)(ws + 65536 + 131072);     // nmols*128*4 = 8 MB

    int segblocks = (nmols + 1 + 255) / 256;
    combo_kernel<<<64 + segblocks, 256, 0, stream>>>(WQ, WK, W, idx, segstart, nmols, total);
    qproj_kernel<<<(nmols + 15) / 16, 256, 0, stream>>>(Q, W, R, nmols);
    // 5x fused: idempotent re-computation; F = (dur_R6 - dur_R4)/4
    for (int rep = 0; rep < 5; ++rep) {
        fused_kernel<<<2048, 256, 0, stream>>>(K, R, segstart, weights, scores, nmols);
    }
}

// Round 7
// 137.656 us; speedup vs baseline: 4.0054x; 4.0054x over previous
//
#include <hip/hip_runtime.h>
#include <hip/hip_bf16.h>

#define QUERY_DIM 128
#define HIDDEN 128

typedef float f32x4 __attribute__((ext_vector_type(4)));

__device__ __forceinline__ float dot4(f32x4 a, f32x4 b) {
    return a.x * b.x + a.y * b.y + a.z * b.z + a.w * b.w;
}

// ---------------------------------------------------------------------------
// Kernel 1 (combo): blocks 0..63  -> W[e][d] = sum_h WQ[h][e]*WK[h][d]
//                   blocks 64..   -> segment starts via binary search
// ---------------------------------------------------------------------------
__global__ __launch_bounds__(256) void combo_kernel(const float* __restrict__ WQ,
                                                    const float* __restrict__ WK,
                                                    float* __restrict__ W,
                                                    const int* __restrict__ idx,
                                                    int* __restrict__ start,
                                                    int nmols, int total) {
    int b = blockIdx.x;
    int t = threadIdx.x;
    if (b < 64) {
        int e = b * 2 + (t >> 7);   // 0..127
        int d = t & 127;
        float acc = 0.f;
#pragma unroll 8
        for (int h = 0; h < HIDDEN; ++h) {
            acc += WQ[h * QUERY_DIM + e] * WK[h * 128 + d];
        }
        W[e * 128 + d] = acc;
    } else {
        int m = (b - 64) * 256 + t;
        if (m > nmols) return;
        if (m == nmols) { start[m] = total; return; }
        int lo = 0, hi = total;
        while (lo < hi) {
            int mid = (lo + hi) >> 1;
            if (idx[mid] < m) lo = mid + 1; else hi = mid;
        }
        start[m] = lo;
    }
}

// ---------------------------------------------------------------------------
// Kernel 2: R = query @ W.  16 rows/block, 256 threads.
// d tiled by 4: per 4-d iteration 4 ds_read_b32 (w, per-lane conflict-free)
// + 8 ds_read_b128 (q, wave-broadcast) = 12 LDS instr for 32 FMA/row-set
// (was 36 scalar reads). ql b128 is 16B-aligned (dg % 4 == 0).
// ---------------------------------------------------------------------------
__global__ __launch_bounds__(256) void qproj_kernel(const float* __restrict__ Q,
                                                    const float* __restrict__ W,
                                                    float* __restrict__ R, int nmols) {
    __shared__ float wl[64 * 128];  // 32 KB (half of W)
    __shared__ float ql[16 * 128];  // 8 KB (16 query rows)
    int t = threadIdx.x;
    int c = t & 127;
    int g = t >> 7;
    long row0 = (long)blockIdx.x * 16;

    for (int i = t * 4; i < 16 * 128; i += 256 * 4) {
        *(float4*)&ql[i] = *(const float4*)&Q[row0 * QUERY_DIM + i];
    }

    float acc[8] = {0.f, 0.f, 0.f, 0.f, 0.f, 0.f, 0.f, 0.f};

    for (int half = 0; half < 2; ++half) {
        __syncthreads();
        for (int i = t * 4; i < 64 * 128; i += 256 * 4) {
            *(float4*)&wl[i] = *(const float4*)&W[half * 64 * 128 + i];
        }
        __syncthreads();
        for (int d = 0; d < 64; d += 4) {
            float w0 = wl[(d + 0) * 128 + c];
            float w1 = wl[(d + 1) * 128 + c];
            float w2 = wl[(d + 2) * 128 + c];
            float w3 = wl[(d + 3) * 128 + c];
            int dg = half * 64 + d;
#pragma unroll
            for (int r = 0; r < 8; ++r) {
                f32x4 q = *(const f32x4*)&ql[(g * 8 + r) * 128 + dg];
                acc[r] += q.x * w0 + q.y * w1 + q.z * w2 + q.w * w3;
            }
        }
    }
#pragma unroll
    for (int r = 0; r < 8; ++r) {
        long row = row0 + g * 8 + r;
        if (row < nmols) R[row * 128 + c] = acc[r];
    }
}

// ---------------------------------------------------------------------------
// Kernel 3 (fused, dominant): per segment scores + stable softmax.
// One wave per segment; half-wave per key row (contiguous 512B).
// Phase 1 unrolled x4: 4 independent 1KB wave-loads issued back-to-back
// (rows kb..kb+7), then 4 interleaved shfl-reduce chains — keeps ~4KB/wave
// in flight instead of 1KB and covers the shfl dead time.
// ---------------------------------------------------------------------------
__global__ __launch_bounds__(256) void fused_kernel(const float* __restrict__ K,
                                                    const float* __restrict__ R,
                                                    const int* __restrict__ start,
                                                    float* __restrict__ weights,
                                                    float* scores,   // no restrict: store+load alias
                                                    int nmols) {
    const int lane = threadIdx.x & 63;
    const int half = lane >> 5;      // 0/1
    const int hl = lane & 31;        // lane within half-wave
    const int wave = (blockIdx.x * 256 + threadIdx.x) >> 6;
    const int nwaves = gridDim.x * 4;
    const float sc = 0.08838834764831845f;  // 1/sqrt(128)

    for (int s = wave; s < nmols; s += nwaves) {
        int s0 = start[s], s1 = start[s + 1];
        if (s0 >= s1) continue;

        f32x4 rfrag = *((const f32x4*)(R + (long)s * 128) + hl);

        // ---- phase 1: scores + running max ----
        float mx = -__builtin_inff();
        int kb = s0;
        for (; kb + 8 <= s1; kb += 8) {
            long k = kb + half;          // this half: rows k, k+2, k+4, k+6
            const f32x4* p0 = (const f32x4*)(K + (k + 0) * 128) + hl;
            const f32x4* p1 = (const f32x4*)(K + (k + 2) * 128) + hl;
            const f32x4* p2 = (const f32x4*)(K + (k + 4) * 128) + hl;
            const f32x4* p3 = (const f32x4*)(K + (k + 6) * 128) + hl;
            f32x4 a0 = __builtin_nontemporal_load(p0);
            f32x4 a1 = __builtin_nontemporal_load(p1);
            f32x4 a2 = __builtin_nontemporal_load(p2);
            f32x4 a3 = __builtin_nontemporal_load(p3);
            float v0 = dot4(a0, rfrag);
            float v1 = dot4(a1, rfrag);
            float v2 = dot4(a2, rfrag);
            float v3 = dot4(a3, rfrag);
#pragma unroll
            for (int off = 16; off > 0; off >>= 1) {
                v0 += __shfl_xor(v0, off, 64);
                v1 += __shfl_xor(v1, off, 64);
                v2 += __shfl_xor(v2, off, 64);
                v3 += __shfl_xor(v3, off, 64);
            }
            v0 *= sc; v1 *= sc; v2 *= sc; v3 *= sc;
            if (hl == 0) {
                scores[k + 0] = v0;
                scores[k + 2] = v1;
                scores[k + 4] = v2;
                scores[k + 6] = v3;
            }
            mx = fmaxf(mx, fmaxf(fmaxf(v0, v1), fmaxf(v2, v3)));
        }
        for (long k = kb + half; k < s1; k += 2) {   // tail (<8 keys)
            f32x4 kv = __builtin_nontemporal_load((const f32x4*)(K + k * 128) + hl);
            float v = dot4(kv, rfrag);
#pragma unroll
            for (int off = 16; off > 0; off >>= 1) v += __shfl_xor(v, off, 64);
            v *= sc;
            if (hl == 0) scores[k] = v;
            mx = fmaxf(mx, v);
        }
        mx = fmaxf(mx, __shfl_xor(mx, 32, 64));

        // make the scores stores visible before re-reading
        asm volatile("s_waitcnt vmcnt(0)" ::: "memory");

        // ---- phase 2: sum of exp (scores L1-hot) ----
        float sum = 0.f;
        for (int i = s0 + lane; i < s1; i += 64) sum += __expf(scores[i] - mx);
#pragma unroll
        for (int off = 32; off > 0; off >>= 1) sum += __shfl_xor(sum, off, 64);
        float inv = 1.0f / sum;

        // ---- phase 3: weights ----
        for (int i = s0 + lane; i < s1; i += 64)
            weights[i] = __expf(scores[i] - mx) * inv;
    }
}

// ---------------------------------------------------------------------------
extern "C" void kernel_launch(void* const* d_in, const int* in_sizes, int n_in,
                              void* d_out, int out_size, void* d_ws, size_t ws_size,
                              hipStream_t stream) {
    const float* Q   = (const float*)d_in[0];
    const float* K   = (const float*)d_in[1];
    const float* WQ  = (const float*)d_in[2];
    const float* WK  = (const float*)d_in[3];
    const int*   idx = (const int*)d_in[4];

    const int nmols = in_sizes[0] / QUERY_DIM;   // 16384
    const int total = in_sizes[4];               // 1048576

    float* weights = (float*)d_out;              // output 0
    float* scores  = (float*)d_out + total;      // output 1

    char* ws = (char*)d_ws;
    float* W        = (float*)ws;                        // 64 KB
    int*   segstart = (int*)(ws + 65536);                // (nmols+1)*4
    float* R        = (float*)(ws + 65536 + 131072);     // nmols*128*4 = 8 MB

    int segblocks = (nmols + 1 + 255) / 256;
    combo_kernel<<<64 + segblocks, 256, 0, stream>>>(WQ, WK, W, idx, segstart, nmols, total);
    qproj_kernel<<<(nmols + 15) / 16, 256, 0, stream>>>(Q, W, R, nmols);
    fused_kernel<<<2048, 256, 0, stream>>>(K, R, segstart, weights, scores, nmols);
}